// Round 11
// baseline (435.028 us; speedup 1.0000x reference)
//
#include <hip/hip_runtime.h>
#include <hip/hip_bf16.h>

#define NN 50000
#define NE 800000
#define FIN 128
#define NHEADS 3
#define NG 1024
#define HD 192

typedef unsigned short ushort_t;
typedef __bf16 bf16x8 __attribute__((ext_vector_type(8)));
typedef float f32x4 __attribute__((ext_vector_type(4)));

__device__ __forceinline__ float bf2f(ushort_t u) {
    union { unsigned int i; float f; } c;
    c.i = ((unsigned int)u) << 16;
    return c.f;
}
__device__ __forceinline__ float bf2f_lo(unsigned int u) {
    union { unsigned int i; float f; } c;
    c.i = u << 16;
    return c.f;
}
__device__ __forceinline__ float bf2f_hi(unsigned int u) {
    union { unsigned int i; float f; } c;
    c.i = u & 0xffff0000u;
    return c.f;
}
__device__ __forceinline__ ushort_t f2bf(float f) {
    __hip_bfloat16 h = __float2bfloat16(f);
    return *reinterpret_cast<ushort_t*>(&h);
}

// ---------------- fused conversions: feats f32->bf16 + 3 weight transposes ----------------
#define F4 (NN * FIN / 4)
#define W1E (FIN * HD)
#define W2E (64 * HD)
#define WLE (HD * 64)
__global__ __launch_bounds__(256) void conv_all_kernel(const float* __restrict__ feats,
                                                       const float* __restrict__ W1,
                                                       const float* __restrict__ W2,
                                                       const float* __restrict__ Wl,
                                                       ushort_t* __restrict__ featsb,
                                                       ushort_t* __restrict__ W1t,
                                                       ushort_t* __restrict__ W2t,
                                                       ushort_t* __restrict__ Wlt) {
    int i = blockIdx.x * 256 + threadIdx.x;
    if (i < F4) {
        float4 v = ((const float4*)feats)[i];
        ushort4 o;
        o.x = f2bf(v.x); o.y = f2bf(v.y); o.z = f2bf(v.z); o.w = f2bf(v.w);
        ((ushort4*)featsb)[i] = o;
        return;
    }
    int t = i - F4;
    if (t < W1E) {  // W1[k][n] -> W1t[n][k], K=FIN, N=HD
        int k = t / HD, n = t - k * HD;
        W1t[n * FIN + k] = f2bf(W1[t]);
        return;
    }
    t -= W1E;
    if (t < W2E) {  // K=64, N=HD
        int k = t / HD, n = t - k * HD;
        W2t[n * 64 + k] = f2bf(W2[t]);
        return;
    }
    t -= W2E;
    if (t < WLE) {  // K=HD, N=64
        int k = t / 64, n = t - k * 64;
        Wlt[n * HD + k] = f2bf(Wl[t]);
    }
}

// ---------------- MFMA GEMM: C[nrows,NT*16] = Ab[nrows,K] @ Wt^T ----------------
// 256 thr = 4 waves, 64 rows/block, wave -> 16 rows x N cols. Register-only, no LDS.
// A frag: row = lane&15, k = (lane>>4)*8+j (contiguous 16B). B frag from Wt[N][K].
// C/D: col=lane&15, row=(lane>>4)*4+reg (verified m89 mapping).
// ATTN=1: write zb bf16 + el4/er4. ATTN=0: xb = bf16(acc+bias) only.
template<int K, int NT, int ATTN>
__global__ __launch_bounds__(256) void mgemm_kernel(const ushort_t* __restrict__ Ab,
                                                    const ushort_t* __restrict__ Wt,
                                                    const float* __restrict__ bias,
                                                    const float* __restrict__ al,
                                                    const float* __restrict__ ar,
                                                    float* __restrict__ el4,
                                                    float* __restrict__ er4,
                                                    ushort_t* __restrict__ xb,
                                                    ushort_t* __restrict__ zb,
                                                    int nrows) {
    constexpr int N = NT * 16;
    const int lane = threadIdx.x & 63;
    const int wid = threadIdx.x >> 6;
    const int row0 = blockIdx.x * 64 + wid * 16;
    const int m = lane & 15;
    const int kg = lane >> 4;

    int rA = row0 + m;
    if (rA > nrows - 1) rA = nrows - 1;
    const ushort_t* arow = Ab + (size_t)rA * K + kg * 8;

    const f32x4 zero4 = {0.f, 0.f, 0.f, 0.f};
    f32x4 acc[NT];
#pragma unroll
    for (int n = 0; n < NT; ++n) acc[n] = zero4;

#pragma unroll
    for (int k0 = 0; k0 < K; k0 += 32) {
        bf16x8 a = *(const bf16x8*)(arow + k0);
#pragma unroll
        for (int n = 0; n < NT; ++n) {
            bf16x8 b = *(const bf16x8*)(Wt + (size_t)(n * 16 + m) * K + k0 + kg * 8);
            acc[n] = __builtin_amdgcn_mfma_f32_16x16x32_bf16(a, b, acc[n], 0, 0, 0);
        }
    }

    const int orow = row0 + kg * 4;

    if (ATTN) {
        float sl[NHEADS][4], sr[NHEADS][4];
#pragma unroll
        for (int h = 0; h < NHEADS; ++h)
#pragma unroll
            for (int r = 0; r < 4; ++r) { sl[h][r] = 0.f; sr[h][r] = 0.f; }
#pragma unroll
        for (int n = 0; n < NT; ++n) {
            float alv = al[n * 16 + m];
            float arv = ar[n * 16 + m];
            const int h = n >> 2;
#pragma unroll
            for (int r = 0; r < 4; ++r) {
                sl[h][r] = fmaf(acc[n][r], alv, sl[h][r]);
                sr[h][r] = fmaf(acc[n][r], arv, sr[h][r]);
            }
        }
#pragma unroll
        for (int off = 1; off < 16; off <<= 1) {
#pragma unroll
            for (int h = 0; h < NHEADS; ++h)
#pragma unroll
                for (int r = 0; r < 4; ++r) {
                    sl[h][r] += __shfl_xor(sl[h][r], off);
                    sr[h][r] += __shfl_xor(sr[h][r], off);
                }
        }
#pragma unroll
        for (int r = 0; r < 4; ++r) {
            int gr = orow + r;
            if (gr < nrows) {
#pragma unroll
                for (int n = 0; n < NT; ++n)
                    zb[(size_t)gr * N + n * 16 + m] = f2bf(acc[n][r]);
                if (m == 0) {
                    *(float4*)(el4 + (size_t)gr * 4) = make_float4(sl[0][r], sl[1][r], sl[2][r], 0.f);
                    *(float4*)(er4 + (size_t)gr * 4) = make_float4(sr[0][r], sr[1][r], sr[2][r], 0.f);
                }
            }
        }
    } else {
#pragma unroll
        for (int r = 0; r < 4; ++r) {
            int gr = orow + r;
            if (gr < nrows) {
#pragma unroll
                for (int n = 0; n < NT; ++n)
                    xb[(size_t)gr * N + n * 16 + m] = f2bf(acc[n][r] + bias[n * 16 + m]);
            }
        }
    }
}

// ---------------- CSR build ----------------
// count: 4 edges/thread (independent atomic chains); store rank = old count.
__global__ __launch_bounds__(256) void count_kernel(const int* __restrict__ dst,
                                                    int* __restrict__ cnt,
                                                    int* __restrict__ rank) {
    int e0 = blockIdx.x * 1024 + threadIdx.x;
#pragma unroll
    for (int k = 0; k < 4; ++k) {
        int e = e0 + k * 256;
        if (e < NE) rank[e] = atomicAdd(&cnt[dst[e]], 1);
    }
}

__global__ __launch_bounds__(256) void scan_block_kernel(const int* __restrict__ cnt,
                                                         int* __restrict__ incl,
                                                         int* __restrict__ bsum, int n) {
    __shared__ int s[256];
    int tid = threadIdx.x;
    int i = blockIdx.x * 256 + tid;
    int v = (i < n) ? cnt[i] : 0;
    s[tid] = v;
    __syncthreads();
#pragma unroll
    for (int off = 1; off < 256; off <<= 1) {
        int add = (tid >= off) ? s[tid - off] : 0;
        __syncthreads();
        s[tid] += add;
        __syncthreads();
    }
    if (i < n) incl[i] = s[tid];
    if (tid == 255) bsum[blockIdx.x] = s[255];
}

// finalize: per-block exclusive prefix of bsum via wave-strided reduce + butterfly.
__global__ __launch_bounds__(256) void finalize_rowptr_kernel(const int* __restrict__ incl,
                                                              const int* __restrict__ bsum,
                                                              int* __restrict__ row_ptr, int n) {
    int b = blockIdx.x;
    int part = 0;
    for (int k = (threadIdx.x & 63); k < b; k += 64) part += bsum[k];
#pragma unroll
    for (int off = 32; off > 0; off >>= 1) part += __shfl_xor(part, off);
    int i = b * 256 + threadIdx.x;
    if (i < n) row_ptr[i + 1] = incl[i] + part;
    if (i == 0) row_ptr[0] = 0;
}

// fill: atomic-free scatter using precomputed rank.
__global__ __launch_bounds__(256) void fill_kernel(const int* __restrict__ src,
                                                   const int* __restrict__ dst,
                                                   const int* __restrict__ row_ptr,
                                                   const int* __restrict__ rank,
                                                   int* __restrict__ srcs_sorted) {
    int e = blockIdx.x * 256 + threadIdx.x;
    if (e < NE) {
        srcs_sorted[row_ptr[dst[e]] + rank[e]] = src[e];
    }
}

// ---------------- aggregation: one wave per dst node, 2 edges/iter, 16B loads ----------------
// Chunk prologue (all 64 lanes): lane i computes exp-scores for edge c0+i, accumulates denom,
// writes p to wave-local padded LDS plds[wid][3][72].
// Inner loop (lanes 0..47): lanes 0-23 handle even edge (j), lanes 24-47 odd edge (j+1);
// each lane loads 16B (8 dims) of its edge's z row -> 24 addresses/edge (was 48),
// 0.5 load instr/edge. Lane l<24 owns dims 8l..8l+7; partial of lane l+24 merged via
// shfl_down(24) at the end.
__global__ __launch_bounds__(256) void aggregate_kernel(const ushort_t* __restrict__ zb,
                                                        const float* __restrict__ el4,
                                                        const float* __restrict__ er4,
                                                        const int* __restrict__ row_ptr,
                                                        const int* __restrict__ srcs,
                                                        const float* __restrict__ bias,
                                                        ushort_t* __restrict__ yb) {
    __shared__ float plds[4][NHEADS][72];
    int node = blockIdx.x * 4 + (threadIdx.x >> 6);
    int lane = threadIdx.x & 63;
    if (node >= NN) return;
    int s0 = row_ptr[node], s1 = row_ptr[node + 1];
    size_t o = (size_t)node * HD;
    const int wid = threadIdx.x >> 6;
    const int g24 = (lane < 48) ? (lane < 24 ? lane : lane - 24) : 0;
    const int halfE = (lane >= 24) ? 1 : 0;     // edge parity handled by this lane
    const int h = g24 >> 3;                     // head of owned dims (8*g24 .. 8*g24+7)
    const int uoff = g24 * 8;                   // ushort offset of owned 16B segment

    float4 erv = *(const float4*)(er4 + (size_t)node * 4);

    float d0 = 0.f, d1 = 0.f, d2 = 0.f;
    float a[8];
#pragma unroll
    for (int t = 0; t < 8; ++t) a[t] = 0.f;

    for (int c0 = s0; c0 < s1; c0 += 64) {
        int i = c0 + lane;
        float p0 = 0.f, p1 = 0.f, p2 = 0.f;
        int s = 0;
        if (i < s1) {
            s = srcs[i];
            float4 elv = *(const float4*)(el4 + (size_t)s * 4);
            float e0 = elv.x + erv.x, e1 = elv.y + erv.y, e2 = elv.z + erv.z;
            e0 = e0 > 0.f ? e0 : 0.2f * e0;
            e1 = e1 > 0.f ? e1 : 0.2f * e1;
            e2 = e2 > 0.f ? e2 : 0.2f * e2;
            p0 = __expf(fminf(e0, 60.f));
            p1 = __expf(fminf(e1, 60.f));
            p2 = __expf(fminf(e2, 60.f));
        }
        d0 += p0; d1 += p1; d2 += p2;
        plds[wid][0][lane] = p0;
        plds[wid][1][lane] = p1;
        plds[wid][2][lane] = p2;
        // wave-local LDS: order write->read within the wave (no __syncthreads;
        // divergent per-wave loop). The waitcnt drains the ds_writes.
        asm volatile("s_waitcnt lgkmcnt(0)" ::: "memory");
        int nch = s1 - c0; if (nch > 64) nch = 64;
        if (lane < 48) {
            const float* prow = &plds[wid][h][halfE];
#pragma unroll 4
            for (int j = 0; j < nch; j += 2) {
                int sjA = __builtin_amdgcn_readlane(s, j);
                int sjB = __builtin_amdgcn_readlane(s, j + 1);
                int sj = halfE ? sjB : sjA;
                uint4 zv = *(const uint4*)(zb + (size_t)sj * HD + uoff);
                float q = prow[j];                 // ds_read_b32: plds[wid][h][j+halfE]
                a[0] = fmaf(q, bf2f_lo(zv.x), a[0]);
                a[1] = fmaf(q, bf2f_hi(zv.x), a[1]);
                a[2] = fmaf(q, bf2f_lo(zv.y), a[2]);
                a[3] = fmaf(q, bf2f_hi(zv.y), a[3]);
                a[4] = fmaf(q, bf2f_lo(zv.z), a[4]);
                a[5] = fmaf(q, bf2f_hi(zv.z), a[5]);
                a[6] = fmaf(q, bf2f_lo(zv.w), a[6]);
                a[7] = fmaf(q, bf2f_hi(zv.w), a[7]);
            }
        }
    }
#pragma unroll
    for (int off = 32; off > 0; off >>= 1) {
        d0 += __shfl_xor(d0, off);
        d1 += __shfl_xor(d1, off);
        d2 += __shfl_xor(d2, off);
    }
    // merge odd-edge partials (lanes 24..47) into lanes 0..23
#pragma unroll
    for (int t = 0; t < 8; ++t) a[t] += __shfl_down(a[t], 24);

    if (lane < 24) {
        float dd = (h == 0) ? d0 : ((h == 1) ? d1 : d2);
        float rinv = 1.0f / dd;
        float4 bb0 = *(const float4*)(bias + uoff);
        float4 bb1 = *(const float4*)(bias + uoff + 4);
        ushort4 ov0, ov1;
        ov0.x = f2bf(a[0] * rinv + bb0.x);
        ov0.y = f2bf(a[1] * rinv + bb0.y);
        ov0.z = f2bf(a[2] * rinv + bb0.z);
        ov0.w = f2bf(a[3] * rinv + bb0.w);
        ov1.x = f2bf(a[4] * rinv + bb1.x);
        ov1.y = f2bf(a[5] * rinv + bb1.y);
        ov1.z = f2bf(a[6] * rinv + bb1.z);
        ov1.w = f2bf(a[7] * rinv + bb1.w);
        *(ushort4*)(yb + o + uoff) = ov0;
        *(ushort4*)(yb + o + uoff + 4) = ov1;
    }
}

// ---------------- pooling (reads bf16 x) ----------------
__global__ __launch_bounds__(256) void pool_kernel(const ushort_t* __restrict__ xb,
                                                   const int* __restrict__ gid,
                                                   float* __restrict__ gsum,
                                                   int* __restrict__ gcnt) {
    int w = blockIdx.x * 4 + (threadIdx.x >> 6);
    int lane = threadIdx.x & 63;
    int n0 = w * 16;
    if (n0 >= NN) return;
    int n1 = n0 + 16; if (n1 > NN) n1 = NN;
    int curg = gid[n0];
    float acc = 0.f;
    int cl = 0;
    for (int n = n0; n < n1; ++n) {
        int g = gid[n];
        if (g != curg) {
            atomicAdd(&gsum[curg * 64 + lane], acc);
            if (lane == 0) atomicAdd(&gcnt[curg], cl);
            acc = 0.f; cl = 0; curg = g;
        }
        acc += bf2f(xb[(size_t)n * 64 + lane]);
        cl++;
    }
    atomicAdd(&gsum[curg * 64 + lane], acc);
    if (lane == 0) atomicAdd(&gcnt[curg], cl);
}

__global__ __launch_bounds__(256) void pool_final_kernel(const float* __restrict__ gsum,
                                                         const int* __restrict__ gcnt,
                                                         float* __restrict__ out) {
    int idx = blockIdx.x * 256 + threadIdx.x;
    if (idx < NG * 64) {
        int g = idx >> 6;
        float c = (float)gcnt[g];
        out[idx] = gsum[idx] / fmaxf(c, 1.0f);
    }
}

// ---------------- launch ----------------
extern "C" void kernel_launch(void* const* d_in, const int* in_sizes, int n_in,
                              void* d_out, int out_size, void* d_ws, size_t ws_size,
                              hipStream_t stream) {
    const float* feats = (const float*)d_in[0];
    const int* src = (const int*)d_in[1];
    const int* dst = (const int*)d_in[2];
    const int* gid = (const int*)d_in[3];
    const float* W1 = (const float*)d_in[4];
    const float* al1 = (const float*)d_in[5];
    const float* ar1 = (const float*)d_in[6];
    const float* b1 = (const float*)d_in[7];
    const float* W2 = (const float*)d_in[8];
    const float* al2 = (const float*)d_in[9];
    const float* ar2 = (const float*)d_in[10];
    const float* b2 = (const float*)d_in[11];
    const float* Wl = (const float*)d_in[12];
    const float* bl = (const float*)d_in[13];
    float* out = (float*)d_out;

    size_t off = 0;
    auto alloc = [&](size_t bytes) -> char* {
        char* p = (char*)d_ws + off;
        off += (bytes + 255) & ~(size_t)255;
        return p;
    };
    ushort_t* featsb = (ushort_t*)alloc((size_t)NN * FIN * 2);
    ushort_t* zb = (ushort_t*)alloc((size_t)NN * HD * 2);
    ushort_t* yb = (ushort_t*)alloc((size_t)NN * HD * 2);
    ushort_t* xb = (ushort_t*)alloc((size_t)NN * 64 * 2);
    float* el4 = (float*)alloc((size_t)NN * 4 * 4);
    float* er4 = (float*)alloc((size_t)NN * 4 * 4);
    ushort_t* W1t = (ushort_t*)alloc((size_t)HD * FIN * 2);  // [192][128]
    ushort_t* W2t = (ushort_t*)alloc((size_t)HD * 64 * 2);   // [192][64]
    ushort_t* Wlt = (ushort_t*)alloc((size_t)64 * HD * 2);   // [64][192]
    int* row_ptr = (int*)alloc((size_t)(NN + 1) * 4);
    int* cnt = (int*)alloc((size_t)NN * 4);
    int* incl = (int*)alloc((size_t)NN * 4);
    int* bsum = (int*)alloc(256 * 4);
    int* rank = (int*)alloc((size_t)NE * 4);
    int* srcs = (int*)alloc((size_t)NE * 4);
    float* gsum = (float*)alloc((size_t)NG * 64 * 4);
    int* gcnt = (int*)alloc((size_t)NG * 4);

    const int nbScan = (NN + 255) / 256;
    const int gridE = (NE + 255) / 256;
    const int gridNode = (NN + 3) / 4;
    const int gridGemm = (NN + 63) / 64;

    // ---- fused input conversions ----
    conv_all_kernel<<<(F4 + W1E + W2E + WLE + 255) / 256, 256, 0, stream>>>(
        feats, W1, W2, Wl, featsb, W1t, W2t, Wlt);

    // ---- CSR build (shared by all 3 convs) ----
    hipMemsetAsync(cnt, 0, (size_t)NN * 4, stream);
    count_kernel<<<(NE + 1023) / 1024, 256, 0, stream>>>(dst, cnt, rank);
    scan_block_kernel<<<nbScan, 256, 0, stream>>>(cnt, incl, bsum, NN);
    finalize_rowptr_kernel<<<nbScan, 256, 0, stream>>>(incl, bsum, row_ptr, NN);
    fill_kernel<<<gridE, 256, 0, stream>>>(src, dst, row_ptr, rank, srcs);

    // ---- conv1 ----
    mgemm_kernel<FIN, 12, 1><<<gridGemm, 256, 0, stream>>>(featsb, W1t, nullptr, al1, ar1,
                                                           el4, er4, nullptr, zb, NN);
    aggregate_kernel<<<gridNode, 256, 0, stream>>>(zb, el4, er4, row_ptr, srcs, b1, yb);
    mgemm_kernel<HD, 4, 0><<<gridGemm, 256, 0, stream>>>(yb, Wlt, bl, nullptr, nullptr,
                                                         nullptr, nullptr, xb, nullptr, NN);

    // ---- conv2, conv3 ----
    for (int it = 0; it < 2; ++it) {
        mgemm_kernel<64, 12, 1><<<gridGemm, 256, 0, stream>>>(xb, W2t, nullptr, al2, ar2,
                                                              el4, er4, nullptr, zb, NN);
        aggregate_kernel<<<gridNode, 256, 0, stream>>>(zb, el4, er4, row_ptr, srcs, b2, yb);
        mgemm_kernel<HD, 4, 0><<<gridGemm, 256, 0, stream>>>(yb, Wlt, bl, nullptr, nullptr,
                                                             nullptr, nullptr, xb, nullptr, NN);
    }

    // ---- avg pooling ----
    hipMemsetAsync(gsum, 0, (size_t)NG * 64 * 4 + (size_t)NG * 4, stream);
    pool_kernel<<<(NN / 16 + 3) / 4 + 1, 256, 0, stream>>>(xb, gid, gsum, gcnt);
    pool_final_kernel<<<(NG * 64 + 255) / 256, 256, 0, stream>>>(gsum, gcnt, out);
}